// Round 2
// 650.044 us; speedup vs baseline: 1.0970x; 1.0970x over previous
//
#include <hip/hip_runtime.h>
#include <stdint.h>

// Problem constants (static per reference)
#define S_TOK   8192
#define MODEL_D 1024
#define N_EXP   64
#define CAP     128         // max(ceil(8192/64*1.0), 8)
#define SHIFT   4096        // int(S * 0.5)
#define SLAB    (N_EXP * CAP)           // 8192 floats per token slab
#define CDSIZE  ((size_t)S_TOK * SLAB)  // 67108864
#define OUT_FILL4 33554448              // float4 count covering out[0..134217792)
#define FILL_SPLIT4  16777216           // k1 zeroes [0,SPLIT), k2 zeroes [SPLIT,OUT_FILL4)
#define FILL_STRIDE4 2097152            // 8192 fill blocks * 256 threads

#define GEMM_BLOCKS 512
#define TPB         16                  // tokens per gemm block

// native clang vector type — __builtin_nontemporal_store rejects HIP's float4 class
typedef float fx4 __attribute__((ext_vector_type(4)));

// d_out layout (float32): [l_aux(1) | combine(CDSIZE) | dispatch(CDSIZE) | exp_counts(64) | unrouted(1)]

// ws offsets (bytes)
#define OFF_EXPERT   0          // int[8192]
#define OFF_GATE     32768      // float[8192]   max-gate value (=1/Z)
#define OFF_KEY      65536      // uint[8192]    sortable importance key
#define OFF_KEY2     98304      // uint[8192]    (expert<<13)|pos
#define OFF_MEPART   131072     // float[512][64] per-block gate column sums
#define OFF_HIST     262144     // int[512][64]   per-block argmax histograms
#define OFF_WGT      393216     // float[256][64][4] repacked weights [d/4][e][d%4]

__device__ __forceinline__ unsigned f2key(float f) {
    // monotonic float->uint transform (ascending float == ascending uint)
    unsigned b = __float_as_uint(f);
    return (b & 0x80000000u) ? ~b : (b | 0x80000000u);
}

// N0: repack wg [64][1024] -> wgT4 [256][64][4] so gemm lanes (lane=expert)
// load 4 consecutive d's as ONE coalesced float4.
__global__ __launch_bounds__(256) void k0_repack(const float* __restrict__ wg,
                                                 float* __restrict__ wgT4) {
    int id0 = blockIdx.x * 256 + threadIdx.x;
#pragma unroll
    for (int i = 0; i < 4; ++i) {
        int id = id0 + i * 16384;            // 64*1024 total
        int e = id >> 10;
        int d = id & 1023;
        wgT4[((d >> 2) * 64 + e) * 4 + (d & 3)] = wg[id];
    }
}

// N1: fused zero-fill of the FIRST HALF of out (blocks >= GEMM_BLOCKS, NT
// stores: streaming zeros must not allocate in L2 — avoids write-allocate +
// eviction double traffic while the harness poison's dirty L2 drains) + gate
// GEMM/softmax/argmax/key + per-block me & histogram partials.
__global__ __launch_bounds__(256) void k1_fill_gemm(
    const float* __restrict__ x, const float* __restrict__ wgT4,
    float* __restrict__ out,
    int* __restrict__ expert_id, float* __restrict__ gate1,
    unsigned* __restrict__ keys, float* __restrict__ me_part,
    int* __restrict__ hist_part)
{
    const int b = blockIdx.x;
    if (b >= GEMM_BLOCKS) {
        const fx4 z = (fx4)(0.f);
        fx4* out4 = (fx4*)out;
        size_t base = (size_t)(b - GEMM_BLOCKS) * 256 + threadIdx.x;
#pragma unroll
        for (int k = 0; k < 8; ++k) {
            // covers [0, FILL_SPLIT4) exactly: base < 2097152, 8 strides
            __builtin_nontemporal_store(z, &out4[base + (size_t)k * FILL_STRIDE4]);
        }
        return;
    }

    __shared__ float xs[TPB][256];   // 16 KB x chunk tile
    __shared__ float lg[TPB][65];    // logits tile, padded
    __shared__ float mrow[TPB], zrow[TPB];
    __shared__ int   exrow[TPB];
    __shared__ int   hist[64];
    __shared__ float mep[4][64];

    const int tid  = threadIdx.x;
    const int lane = tid & 63;       // expert index
    const int wv   = tid >> 6;
    const int tok0 = b * TPB;

    const float4* xg  = (const float4*)x;
    const float4* wg4 = (const float4*)wgT4;

    float acc[4] = {0.f, 0.f, 0.f, 0.f};

    for (int chunk = 0; chunk < 4; ++chunk) {
        __syncthreads();   // protect xs from previous chunk's readers
#pragma unroll
        for (int i = 0; i < 4; ++i) {
            int linear = tid + 256 * i;          // 0..1023
            int t  = linear >> 6;
            int c4 = linear & 63;
            ((float4*)xs)[t * 64 + c4] = xg[(size_t)(tok0 + t) * 256 + chunk * 64 + c4];
        }
        __syncthreads();

#pragma unroll 4
        for (int dd = 0; dd < 256; dd += 4) {
            int d = chunk * 256 + dd;
            float4 w = wg4[(d >> 2) * 64 + lane];    // coalesced: lanes consecutive
#pragma unroll
            for (int t = 0; t < 4; ++t) {
                float4 xv = *(const float4*)&xs[wv * 4 + t][dd];  // LDS broadcast
                acc[t] = fmaf(xv.x, w.x, acc[t]);
                acc[t] = fmaf(xv.y, w.y, acc[t]);
                acc[t] = fmaf(xv.z, w.z, acc[t]);
                acc[t] = fmaf(xv.w, w.w, acc[t]);
            }
        }
    }
#pragma unroll
    for (int t = 0; t < 4; ++t) lg[wv * 4 + t][lane] = acc[t];
    __syncthreads();

    if (tid < 64) hist[tid] = 0;
    if (tid < TPB) {
        const int t = tid;
        float m = lg[t][0]; int am = 0;
        for (int e = 1; e < 64; ++e) {
            float v = lg[t][e];
            if (v > m) { m = v; am = e; }   // strict > : first-occurrence argmax (jnp)
        }
        float z = 0.f;
        for (int e = 0; e < 64; ++e) z += expf(lg[t][e] - m);
        float rz = 1.0f / z;                // = max gate value
        mrow[t] = m; zrow[t] = rz; exrow[t] = am;
        int sG = tok0 + t;
        expert_id[sG] = am;
        gate1[sG] = rz;
        keys[sG] = f2key(-rz);              // importance = -maxgate, ascending
    }
    __syncthreads();

    if (tid < TPB) atomicAdd(&hist[exrow[tid]], 1);
    {   // me column partials: thread (e = tid&63, tg = tid>>6)
        const int e = tid & 63, tg = tid >> 6;
        float p = 0.f;
        for (int t = tg; t < TPB; t += 4) p += expf(lg[t][e] - mrow[t]) * zrow[t];
        mep[tg][e] = p;
    }
    __syncthreads();

    if (tid < 64) {
        me_part[b * 64 + tid] = mep[0][tid] + mep[1][tid] + mep[2][tid] + mep[3][tid];
        hist_part[b * 64 + tid] = hist[tid];
    }
}

// N2: blocks 0..255 — global rank by (importance key, index), pos=(rank+SHIFT)&8191,
// emit key2=(expert<<13)|pos (O(S^2) count, all keys in LDS, bank-phase swizzled).
// Blocks 256.. — zero-fill the SECOND HALF of out (NT stores), overlapping the
// rank pass and running after the poison's L2 writeback has largely drained.
// Scalars moved to N3: they live inside the float4 range this kernel zeroes.
__global__ __launch_bounds__(256) void k2_rank_fill(
    const unsigned* __restrict__ keys, const int* __restrict__ expert_id,
    unsigned* __restrict__ key2, float* __restrict__ out)
{
    const int tid = threadIdx.x;
    const int b = blockIdx.x;
    if (b >= 256) {
        const fx4 z = (fx4)(0.f);
        fx4* out4 = (fx4*)out;
        size_t base = (size_t)FILL_SPLIT4 + (size_t)(b - 256) * 256 + tid;
#pragma unroll
        for (int k = 0; k < 9; ++k) {
            size_t i = base + (size_t)k * FILL_STRIDE4;
            if (i < OUT_FILL4) __builtin_nontemporal_store(z, &out4[i]);
        }
        return;
    }

    __shared__ uint4 k4[2048];   // all 8192 keys, 32 KB
    const uint4* kg = (const uint4*)keys;
    for (int i = tid; i < 2048; i += 256) k4[i] = kg[i];
    __syncthreads();

    const int sl = tid >> 3, part = tid & 7;   // 32 tokens/block, 8 scan-threads/token
    const int sG = b * 32 + sl;
    const unsigned myk = ((const unsigned*)k4)[sG];
    int cnt = 0;
    const int qbase = part * 256;
    for (int q = 0; q < 256; ++q) {
        int qq = (q + part) & 255;             // bank-phase swizzle (parts span banks)
        uint4 v = k4[qbase + qq];
        int j = (qbase + qq) * 4;
        cnt += (v.x < myk) || (v.x == myk && (j + 0) < sG);
        cnt += (v.y < myk) || (v.y == myk && (j + 1) < sG);
        cnt += (v.z < myk) || (v.z == myk && (j + 2) < sG);
        cnt += (v.w < myk) || (v.w == myk && (j + 3) < sG);
    }
    cnt += __shfl_down(cnt, 4);
    cnt += __shfl_down(cnt, 2);
    cnt += __shfl_down(cnt, 1);
    if (part == 0) {
        int pos = (cnt + SHIFT) & (S_TOK - 1);
        key2[sG] = ((unsigned)expert_id[sG] << 13) | (unsigned)pos;
    }
}

// N3: blocks 0..255 — loc = within-expert rank by pos; one-hot scatter into the
// (now fully zeroed) out. Block 256 — all scalar outputs: l_aux, exp_counts,
// unrouted (uses: dropped = S - sum_e min(count_e, CAP); per-expert ranks are a
// bijection 0..count_e-1, so drops are exactly the overflow). Scalar indices
// are disjoint from the scatter's combine/dispatch slabs.
__global__ __launch_bounds__(256) void k3_loc_scatter_scalars(
    const unsigned* __restrict__ key2, const float* __restrict__ gate1,
    const float* __restrict__ me_part, const int* __restrict__ hist_part,
    float* __restrict__ out)
{
    const int tid = threadIdx.x;
    if (blockIdx.x == 256) {
        __shared__ float msum[4][64];
        __shared__ int   hsum[4][64];
        __shared__ float contrib[64];
        __shared__ int   keep[64];
        const int e = tid & 63, qt = tid >> 6;
        float ms = 0.f; int hs = 0;
        for (int p = qt * 128; p < qt * 128 + 128; ++p) {
            ms += me_part[p * 64 + e];
            hs += hist_part[p * 64 + e];
        }
        msum[qt][e] = ms; hsum[qt][e] = hs;
        __syncthreads();
        if (tid < 64) {
            float m = msum[0][tid] + msum[1][tid] + msum[2][tid] + msum[3][tid];
            int   h = hsum[0][tid] + hsum[1][tid] + hsum[2][tid] + hsum[3][tid];
            out[1 + 2 * CDSIZE + tid] = (float)h;                          // exp_counts
            contrib[tid] = (m * (1.0f / S_TOK)) * ((float)h * (1.0f / S_TOK));
            keep[tid] = (h < CAP) ? h : CAP;
        }
        __syncthreads();
        if (tid == 0) {
            float sum = 0.f; int kept = 0;
            for (int i = 0; i < 64; ++i) { sum += contrib[i]; kept += keep[i]; }
            out[0] = sum * (float)N_EXP * 0.01f;                           // l_aux
            out[1 + 2 * CDSIZE + 64] = (float)(S_TOK - kept) * (1.0f / S_TOK); // unrouted
        }
        return;
    }

    __shared__ uint4 k4[2048];
    const uint4* kg = (const uint4*)key2;
    for (int i = tid; i < 2048; i += 256) k4[i] = kg[i];
    __syncthreads();

    const int sl = tid >> 3, part = tid & 7;
    const int sG = blockIdx.x * 32 + sl;
    const unsigned myk = ((const unsigned*)k4)[sG];
    const unsigned lo = myk & ~8191u;   // expert<<13
    int cnt = 0;
    const int qbase = part * 256;
    for (int q = 0; q < 256; ++q) {
        int qq = (q + part) & 255;
        uint4 v = k4[qbase + qq];
        cnt += (v.x >= lo) && (v.x < myk);
        cnt += (v.y >= lo) && (v.y < myk);
        cnt += (v.z >= lo) && (v.z < myk);
        cnt += (v.w >= lo) && (v.w < myk);
    }
    cnt += __shfl_down(cnt, 4);
    cnt += __shfl_down(cnt, 2);
    cnt += __shfl_down(cnt, 1);
    if (part == 0 && cnt < CAP) {
        unsigned e = myk >> 13;
        size_t idx = 1 + (size_t)sG * SLAB + (size_t)e * CAP + (unsigned)cnt;
        out[idx] = gate1[sG];            // combine_weights one-hot
        out[idx + CDSIZE] = 1.0f;        // dispatch_mask one-hot
    }
}

extern "C" void kernel_launch(void* const* d_in, const int* in_sizes, int n_in,
                              void* d_out, int out_size, void* d_ws, size_t ws_size,
                              hipStream_t stream) {
    (void)in_sizes; (void)n_in; (void)out_size; (void)ws_size;
    const float* x  = (const float*)d_in[0];
    const float* wg = (const float*)d_in[1];
    float* out = (float*)d_out;
    char* ws = (char*)d_ws;

    int*      expert_id = (int*)(ws + OFF_EXPERT);
    float*    gate1     = (float*)(ws + OFF_GATE);
    unsigned* keys      = (unsigned*)(ws + OFF_KEY);
    unsigned* key2      = (unsigned*)(ws + OFF_KEY2);
    float*    me_part   = (float*)(ws + OFF_MEPART);
    int*      hist_part = (int*)(ws + OFF_HIST);
    float*    wgT4      = (float*)(ws + OFF_WGT);

    hipLaunchKernelGGL(k0_repack,             dim3(64),                 dim3(256), 0, stream, wg, wgT4);
    hipLaunchKernelGGL(k1_fill_gemm,          dim3(GEMM_BLOCKS + 8192), dim3(256), 0, stream,
                       x, wgT4, out, expert_id, gate1, keys, me_part, hist_part);
    hipLaunchKernelGGL(k2_rank_fill,          dim3(256 + 8192),         dim3(256), 0, stream,
                       keys, expert_id, key2, out);
    hipLaunchKernelGGL(k3_loc_scatter_scalars, dim3(257),               dim3(256), 0, stream,
                       key2, gate1, me_part, hist_part, out);
}